// Round 9
// baseline (121.504 us; speedup 1.0000x reference)
//
#include <hip/hip_runtime.h>

#define N_SAMPLES 65536
#define C_CLASSES 256
#define D_DIM     1024
#define ALPHA_C   1.0f
#define GAMMA_C   0.01f
#define LCAP      1024     // per-class index list capacity (mean 256, sd 16)
#define NSW       6        // streaming waves per block (waves 0..5); 6,7 do denom

// One block per class, 512 threads (8 waves). Single dispatch, no workspace.
// Wave specialization: waves 0-5 stream features while waves 6-7 build the
// sq/dot table for denom -> denom latency hides under the HBM stream.
__global__ __launch_bounds__(512, 2) void fused_kernel(
    const float* __restrict__ features,
    const int*   __restrict__ labels, int lab_stride,
    const float* __restrict__ cluster,
    const float* __restrict__ cls_w,
    float* __restrict__ loss_out,
    float* __restrict__ out_cluster)
{
    __shared__ int   list_[LCAP];                  // 4 KB
    __shared__ float nume_lds[LCAP];               // 4 KB
    __shared__ int   s_cnt;
    __shared__ float s_denom;
    __shared__ alignas(16) float cc[D_DIM];        // 4 KB (my cluster row)
    __shared__ float sqv[C_CLASSES];               // 1 KB
    __shared__ float dotv[C_CLASSES];              // 1 KB
    __shared__ alignas(16) float comb[NSW][D_DIM]; // 24 KB (stream-wave dsum)

    const int c = blockIdx.x;
    const int t = threadIdx.x;
    const int w = t >> 6, lane = t & 63;

    if (t == 0) s_cnt = 0;
    // my cluster row -> LDS (overlaps with compaction loads below)
    if (t < 256) ((float4*)cc)[t] = ((const float4*)(cluster + (size_t)c * D_DIM))[t];
    __syncthreads();

    // ---------------- A: ballot compaction of this class's samples ----------
#define COMPACT4(m0, m1, m2, m3, s0)                                         \
    {                                                                        \
        unsigned long long b0 = __ballot(m0), b1 = __ballot(m1);             \
        unsigned long long b2 = __ballot(m2), b3 = __ballot(m3);             \
        int tot = __popcll(b0) + __popcll(b1) + __popcll(b2) + __popcll(b3); \
        if (tot) {                                                           \
            int bb = 0;                                                      \
            if (lane == 0) bb = atomicAdd(&s_cnt, tot);                      \
            bb = __shfl(bb, 0, 64);                                          \
            unsigned long long lm = (1ull << lane) - 1ull;                   \
            int p = bb + __popcll(b0 & lm) + __popcll(b1 & lm)               \
                       + __popcll(b2 & lm) + __popcll(b3 & lm);              \
            if (m0) { if (p < LCAP) list_[p] = (s0);     ++p; }              \
            if (m1) { if (p < LCAP) list_[p] = (s0) + 1; ++p; }              \
            if (m2) { if (p < LCAP) list_[p] = (s0) + 2; ++p; }              \
            if (m3) { if (p < LCAP) list_[p] = (s0) + 3; ++p; }              \
        }                                                                    \
    }

    if (lab_stride == 2) {            // int64 labels: int4 = 2 labels (low words x,z)
        const int4* lab4 = (const int4*)labels;
        for (int iter = 0; iter < 32; ++iter) {
            int chunk = iter * 8 + w;            // 0..255 chunks of 256 samples
            int s0 = chunk * 256 + lane * 4;
            int4 v0 = lab4[(s0 >> 1)];
            int4 v1 = lab4[(s0 >> 1) + 1];
            COMPACT4(v0.x == c, v0.z == c, v1.x == c, v1.z == c, s0);
        }
    } else {                          // int32 labels: int4 = 4 labels
        const int4* lab4 = (const int4*)labels;
        for (int iter = 0; iter < 32; ++iter) {
            int chunk = iter * 8 + w;
            int s0 = chunk * 256 + lane * 4;
            int4 v = lab4[s0 >> 2];
            COMPACT4(v.x == c, v.y == c, v.z == c, v.w == c, s0);
        }
    }
#undef COMPACT4
    __syncthreads();
    const int cnt = (s_cnt > LCAP) ? LCAP : s_cnt;
    const float4* cc4 = (const float4*)cc;

    if (w < NSW) {
        // -------- B1 (waves 0..5): stream feature rows, park raw nume -------
        float4 ck[4];
#pragma unroll
        for (int j = 0; j < 4; ++j) ck[j] = cc4[j * 64 + lane];

        float4 dsum[4];
#pragma unroll
        for (int j = 0; j < 4; ++j) dsum[j] = make_float4(0.f, 0.f, 0.f, 0.f);

        int niter = (cnt > w) ? ((cnt - w - 1) / NSW + 1) : 0;

#define LOADROW(buf, idx)                                                    \
    {                                                                        \
        const float4* f_ = (const float4*)(features + (size_t)(idx) * D_DIM);\
        _Pragma("unroll")                                                    \
        for (int j = 0; j < 4; ++j) buf[j] = f_[j * 64 + lane];              \
    }
#define COMPUTE(buf, pos)                                                    \
    {                                                                        \
        float nume = 0.f;                                                    \
        _Pragma("unroll")                                                    \
        for (int j = 0; j < 4; ++j) {                                        \
            float dx = buf[j].x - ck[j].x, dy = buf[j].y - ck[j].y;          \
            float dz = buf[j].z - ck[j].z, dw = buf[j].w - ck[j].w;          \
            dsum[j].x += dx; dsum[j].y += dy;                                \
            dsum[j].z += dz; dsum[j].w += dw;                                \
            nume += dx * dx + dy * dy + dz * dz + dw * dw;                   \
        }                                                                    \
        _Pragma("unroll")                                                    \
        for (int m = 32; m >= 1; m >>= 1) nume += __shfl_xor(nume, m, 64);   \
        if (lane == 0) nume_lds[pos] = nume;                                 \
    }

        float4 bufA[4], bufB[4];
        int ia = (0 < niter) ? list_[w] : -1;
        int ib = (1 < niter) ? list_[w + NSW] : -1;
        if (ia >= 0) LOADROW(bufA, ia);
        int n = 0;
        while (n + 1 < niter) {
            LOADROW(bufB, ib);                                   // prefetch n+1
            int ic = (n + 2 < niter) ? list_[w + (n + 2) * NSW] : -1;
            COMPUTE(bufA, w + n * NSW);                          // compute n
            if (ic >= 0) LOADROW(bufA, ic);                      // prefetch n+2
            int id = (n + 3 < niter) ? list_[w + (n + 3) * NSW] : -1;
            COMPUTE(bufB, w + (n + 1) * NSW);                    // compute n+1
            ia = ic; ib = id; n += 2;
        }
        if (n < niter) COMPUTE(bufA, w + n * NSW);               // odd tail
#undef LOADROW
#undef COMPUTE

        float4* cwv = (float4*)comb[w];
#pragma unroll
        for (int j = 0; j < 4; ++j) cwv[j * 64 + lane] = dsum[j];
    } else {
        // -------- B2 (waves 6,7): sq/dot table, 128 rows each ---------------
        int wv = w - NSW;                      // 0 or 1
        int r0 = wv * 128;
#pragma unroll 2
        for (int rr = 0; rr < 128; ++rr) {
            int r = r0 + rr;
            const float4* row = (const float4*)(cluster + (size_t)r * D_DIM);
            float sq = 0.f, dt = 0.f;
#pragma unroll
            for (int j = 0; j < 4; ++j) {
                float4 v = row[j * 64 + lane];
                float4 a = cc4[j * 64 + lane];
                sq += v.x * v.x + v.y * v.y + v.z * v.z + v.w * v.w;
                dt += v.x * a.x + v.y * a.y + v.z * a.z + v.w * a.w;
            }
#pragma unroll
            for (int m = 32; m >= 1; m >>= 1) {
                sq += __shfl_xor(sq, m, 64);
                dt += __shfl_xor(dt, m, 64);
            }
            if (lane == 0) { sqv[r] = sq; dotv[r] = dt; }
        }
    }
    __syncthreads();

    // ---------------- C: finish denom (64 lanes) ----------------------------
    if (t < 64) {
        float sqc = sqv[c];
        float s = 0.f;
#pragma unroll
        for (int jj = 0; jj < 4; ++jj) {
            int j = jj * 64 + lane;
            float p = sqc + sqv[j] - 2.f * dotv[j];
            s += (p > 0.f ? p : 0.f);
        }
#pragma unroll
        for (int m = 32; m >= 1; m >>= 1) s += __shfl_xor(s, m, 64);
        if (lane == 0) s_denom = s + ALPHA_C;
    }
    __syncthreads();
    const float inv_dnm = 1.0f / s_denom;

    // ---------------- D: scatter loss + direct out_cluster store ------------
    for (int j = t; j < cnt; j += 512)
        loss_out[list_[j]] = nume_lds[j] * inv_dnm;

    if (t < 256) {
        float sc_ = GAMMA_C * cls_w[c] * inv_dnm;
        float4 s = make_float4(0.f, 0.f, 0.f, 0.f);
#pragma unroll
        for (int r = 0; r < NSW; ++r) {
            float4 u = ((const float4*)comb[r])[t];
            s.x += u.x; s.y += u.y; s.z += u.z; s.w += u.w;
        }
        float4 cv = cc4[t];
        float4 o;
        o.x = cv.x - sc_ * s.x;
        o.y = cv.y - sc_ * s.y;
        o.z = cv.z - sc_ * s.z;
        o.w = cv.w - sc_ * s.w;
        ((float4*)(out_cluster + (size_t)c * D_DIM))[t] = o;
    }
}

// ---------------------------------------------------------------------------
extern "C" void kernel_launch(void* const* d_in, const int* in_sizes, int n_in,
                              void* d_out, int out_size, void* d_ws, size_t ws_size,
                              hipStream_t stream) {
    const float* features = (const float*)d_in[0];
    const int*   labels   = (const int*)d_in[1];
    const float* cluster  = (const float*)d_in[2];
    const float* cls_w    = (const float*)d_in[3];
    int lab_stride = in_sizes[1] / N_SAMPLES;   // 1 if int32 words, 2 if int64 words
    if (lab_stride < 1) lab_stride = 1;

    float* loss_out    = (float*)d_out;                 // N floats
    float* out_cluster = (float*)d_out + N_SAMPLES;     // C*D floats

    fused_kernel<<<C_CLASSES, 512, 0, stream>>>(features, labels, lab_stride,
                                                cluster, cls_w, loss_out, out_cluster);
}

// Round 10
// 65.504 us; speedup vs baseline: 1.8549x; 1.8549x over previous
//
#include <hip/hip_runtime.h>

#define N_SAMPLES 65536
#define C_CLASSES 256
#define D_DIM     1024
#define ALPHA_C   1.0f
#define GAMMA_C   0.01f
#define LCAP      1024     // per-class index list capacity (mean 256, sd 16)
#define NW        16       // waves per block (1024 threads)

// One block per class, 1024 threads (16 waves). Single dispatch, no workspace.
// R8 structure (phases use ALL waves) at 2x occupancy: 16 waves/CU hide the
// dependent-load latency in compaction, denom, and the feature stream.
__global__ __launch_bounds__(1024, 1) void fused_kernel(
    const float* __restrict__ features,
    const int*   __restrict__ labels, int lab_stride,
    const float* __restrict__ cluster,
    const float* __restrict__ cls_w,
    float* __restrict__ loss_out,
    float* __restrict__ out_cluster)
{
    __shared__ int   list_[LCAP];                  // 4 KB
    __shared__ int   s_cnt;
    __shared__ float s_denom;
    __shared__ alignas(16) float cc[D_DIM];        // 4 KB (my cluster row)
    __shared__ float sqv[C_CLASSES];               // 1 KB
    __shared__ float dotv[C_CLASSES];              // 1 KB
    __shared__ alignas(16) float comb[NW][D_DIM];  // 64 KB (wave dsum combine)

    const int c = blockIdx.x;
    const int t = threadIdx.x;
    const int w = t >> 6, lane = t & 63;

    if (t == 0) s_cnt = 0;
    if (t < 256) ((float4*)cc)[t] = ((const float4*)(cluster + (size_t)c * D_DIM))[t];
    __syncthreads();

    // ---------------- A: ballot compaction of this class's samples ----------
#define COMPACT4(m0, m1, m2, m3, s0)                                         \
    {                                                                        \
        unsigned long long b0 = __ballot(m0), b1 = __ballot(m1);             \
        unsigned long long b2 = __ballot(m2), b3 = __ballot(m3);             \
        int tot = __popcll(b0) + __popcll(b1) + __popcll(b2) + __popcll(b3); \
        if (tot) {                                                           \
            int bb = 0;                                                      \
            if (lane == 0) bb = atomicAdd(&s_cnt, tot);                      \
            bb = __shfl(bb, 0, 64);                                          \
            unsigned long long lm = (1ull << lane) - 1ull;                   \
            int p = bb + __popcll(b0 & lm) + __popcll(b1 & lm)               \
                       + __popcll(b2 & lm) + __popcll(b3 & lm);              \
            if (m0) { if (p < LCAP) list_[p] = (s0);     ++p; }              \
            if (m1) { if (p < LCAP) list_[p] = (s0) + 1; ++p; }              \
            if (m2) { if (p < LCAP) list_[p] = (s0) + 2; ++p; }              \
            if (m3) { if (p < LCAP) list_[p] = (s0) + 3; ++p; }              \
        }                                                                    \
    }

    if (lab_stride == 2) {            // int64 labels: int4 = 2 labels (low words x,z)
        const int4* lab4 = (const int4*)labels;
        for (int iter = 0; iter < 16; ++iter) {
            int chunk = iter * NW + w;           // 0..255 chunks of 256 samples
            int s0 = chunk * 256 + lane * 4;
            int4 v0 = lab4[(s0 >> 1)];
            int4 v1 = lab4[(s0 >> 1) + 1];
            COMPACT4(v0.x == c, v0.z == c, v1.x == c, v1.z == c, s0);
        }
    } else {                          // int32 labels: int4 = 4 labels
        const int4* lab4 = (const int4*)labels;
        for (int iter = 0; iter < 16; ++iter) {
            int chunk = iter * NW + w;
            int s0 = chunk * 256 + lane * 4;
            int4 v = lab4[s0 >> 2];
            COMPACT4(v.x == c, v.y == c, v.z == c, v.w == c, s0);
        }
    }
#undef COMPACT4
    __syncthreads();
    const int cnt = (s_cnt > LCAP) ? LCAP : s_cnt;
    const float4* cc4 = (const float4*)cc;

    // ---------------- B: denom (sq/dot over all rows, 16 rows/wave) ---------
    for (int r = w; r < C_CLASSES; r += NW) {
        const float4* row = (const float4*)(cluster + (size_t)r * D_DIM);
        float sq = 0.f, dt = 0.f;
#pragma unroll
        for (int j = 0; j < 4; ++j) {
            float4 v = row[j * 64 + lane];
            float4 a = cc4[j * 64 + lane];
            sq += v.x * v.x + v.y * v.y + v.z * v.z + v.w * v.w;
            dt += v.x * a.x + v.y * a.y + v.z * a.z + v.w * a.w;
        }
#pragma unroll
        for (int m = 32; m >= 1; m >>= 1) {
            sq += __shfl_xor(sq, m, 64);
            dt += __shfl_xor(dt, m, 64);
        }
        if (lane == 0) { sqv[r] = sq; dotv[r] = dt; }
    }
    __syncthreads();

    if (t < 64) {
        float sqc = sqv[c];
        float s = 0.f;
#pragma unroll
        for (int jj = 0; jj < 4; ++jj) {
            int j = jj * 64 + lane;
            float p = sqc + sqv[j] - 2.f * dotv[j];
            s += (p > 0.f ? p : 0.f);
        }
#pragma unroll
        for (int m = 32; m >= 1; m >>= 1) s += __shfl_xor(s, m, 64);
        if (lane == 0) s_denom = s + ALPHA_C;
    }
    __syncthreads();
    const float inv_dnm = 1.0f / s_denom;

    // ---------------- C: stream this class's feature rows -------------------
    float4 ck[4];
#pragma unroll
    for (int j = 0; j < 4; ++j) ck[j] = cc4[j * 64 + lane];

    float4 dsum[4];
#pragma unroll
    for (int j = 0; j < 4; ++j) dsum[j] = make_float4(0.f, 0.f, 0.f, 0.f);

    int niter = (cnt > w) ? ((cnt - w - 1) / NW + 1) : 0;   // wave w: w, w+16, ...

#define LOADROW(buf, idx)                                                    \
    {                                                                        \
        const float4* f_ = (const float4*)(features + (size_t)(idx) * D_DIM);\
        _Pragma("unroll")                                                    \
        for (int j = 0; j < 4; ++j) buf[j] = f_[j * 64 + lane];              \
    }
#define COMPUTE(buf, idx)                                                    \
    {                                                                        \
        float nume = 0.f;                                                    \
        _Pragma("unroll")                                                    \
        for (int j = 0; j < 4; ++j) {                                        \
            float dx = buf[j].x - ck[j].x, dy = buf[j].y - ck[j].y;          \
            float dz = buf[j].z - ck[j].z, dw = buf[j].w - ck[j].w;          \
            dsum[j].x += dx; dsum[j].y += dy;                                \
            dsum[j].z += dz; dsum[j].w += dw;                                \
            nume += dx * dx + dy * dy + dz * dz + dw * dw;                   \
        }                                                                    \
        _Pragma("unroll")                                                    \
        for (int m = 32; m >= 1; m >>= 1) nume += __shfl_xor(nume, m, 64);   \
        if (lane == 0) loss_out[idx] = nume * inv_dnm;                       \
    }

    float4 bufA[4], bufB[4];
    int ia = (0 < niter) ? list_[w] : -1;
    int ib = (1 < niter) ? list_[w + NW] : -1;
    if (ia >= 0) LOADROW(bufA, ia);
    int n = 0;
    while (n + 1 < niter) {
        LOADROW(bufB, ib);                                   // prefetch n+1
        int ic = (n + 2 < niter) ? list_[w + (n + 2) * NW] : -1;
        COMPUTE(bufA, ia);                                   // compute n
        if (ic >= 0) LOADROW(bufA, ic);                      // prefetch n+2
        int id = (n + 3 < niter) ? list_[w + (n + 3) * NW] : -1;
        COMPUTE(bufB, ib);                                   // compute n+1
        ia = ic; ib = id; n += 2;
    }
    if (n < niter) COMPUTE(bufA, ia);                        // odd tail
#undef LOADROW
#undef COMPUTE

    // ---------------- D: combine dsum across 16 waves, direct store ---------
    {
        float4* cwv = (float4*)comb[w];
#pragma unroll
        for (int j = 0; j < 4; ++j) cwv[j * 64 + lane] = dsum[j];
    }
    __syncthreads();
    if (t < 256) {
        float sc_ = GAMMA_C * cls_w[c] * inv_dnm;
        float4 s = make_float4(0.f, 0.f, 0.f, 0.f);
#pragma unroll
        for (int r = 0; r < NW; ++r) {
            float4 u = ((const float4*)comb[r])[t];
            s.x += u.x; s.y += u.y; s.z += u.z; s.w += u.w;
        }
        float4 cv = cc4[t];
        float4 o;
        o.x = cv.x - sc_ * s.x;
        o.y = cv.y - sc_ * s.y;
        o.z = cv.z - sc_ * s.z;
        o.w = cv.w - sc_ * s.w;
        ((float4*)(out_cluster + (size_t)c * D_DIM))[t] = o;
    }
}

// ---------------------------------------------------------------------------
extern "C" void kernel_launch(void* const* d_in, const int* in_sizes, int n_in,
                              void* d_out, int out_size, void* d_ws, size_t ws_size,
                              hipStream_t stream) {
    const float* features = (const float*)d_in[0];
    const int*   labels   = (const int*)d_in[1];
    const float* cluster  = (const float*)d_in[2];
    const float* cls_w    = (const float*)d_in[3];
    int lab_stride = in_sizes[1] / N_SAMPLES;   // 1 if int32 words, 2 if int64 words
    if (lab_stride < 1) lab_stride = 1;

    float* loss_out    = (float*)d_out;                 // N floats
    float* out_cluster = (float*)d_out + N_SAMPLES;     // C*D floats

    fused_kernel<<<C_CLASSES, 1024, 0, stream>>>(features, labels, lab_stride,
                                                 cluster, cls_w, loss_out, out_cluster);
}